// Round 4
// baseline (531.885 us; speedup 1.0000x reference)
//
#include <hip/hip_runtime.h>
#include <stdint.h>

// CondConceptSampler: single-query attention per (b,g) with GroupNorm'd q,k.
// Algebra: GN(k) affine per (b,g) -> softmax(sim) depends only on
// rs * (w . x[:,n]) with w[c] = sum_s qhat[s]*g2[s]*Wk[s,c]; mean/beta drop out.
// rs needs Var(K) over (s,n):  SumK  = <colsum(Wk), rowsum(X)>   (exact, fp32)
//                              SumK2 = <M, X X^T>, M = Wk^T Wk   (bf16 MFMA Gram)
// R4: persistent streams — 512 blocks (2/CU), 8 chunks each, explicit register
// double-buffer prefetch across chunk iterations; Gram accumulated across the
// whole block; reductions amortized to once per block. kD walks chunks in
// reverse for L3 (Infinity Cache) reuse of kB's residue.
//
// B=8 G=32 BW=64 S=64 CD=256 N=4096.  x: [8,2048,4096] fp32 (268 MB).

#define EPS 1e-5f
#define NN 4096
#define NSTR 264   // LDS tile row stride in shorts (528B = 33*16B)

typedef __bf16 bf16x8 __attribute__((ext_vector_type(8)));
typedef float f32x4 __attribute__((ext_vector_type(4)));

// ---- Kernel A: q-path -> w_all[bg][c] --------------------------------------
__global__ __launch_bounds__(64) void kA(const float* __restrict__ sent,
                                         const float* __restrict__ Wq,
                                         const float* __restrict__ Wk,
                                         const float* __restrict__ g1,
                                         const float* __restrict__ b1,
                                         const float* __restrict__ g2,
                                         float* __restrict__ w_all) {
  int bg = blockIdx.x; int b = bg >> 5; int g = bg & 31;
  int t = threadIdx.x;                       // t = s index (one wave)
  const float* wqrow = Wq + (size_t)(g * 64 + t) * 256;
  const float* se = sent + b * 256;
  float q = 0.f;
  for (int c = 0; c < 256; c += 4) {
    float4 wv = *(const float4*)(wqrow + c);
    q += se[c] * wv.x + se[c + 1] * wv.y + se[c + 2] * wv.z + se[c + 3] * wv.w;
  }
  float s = q;
  for (int off = 32; off; off >>= 1) s += __shfl_xor(s, off);
  float mu = s * (1.f / 64.f);
  float d = q - mu;
  float v = d * d;
  for (int off = 32; off; off >>= 1) v += __shfl_xor(v, off);
  float rsq = rsqrtf(v * (1.f / 64.f) + EPS);
  int gs = g * 64 + t;
  float qg2 = (d * rsq * g1[gs] + b1[gs]) * g2[gs];  // coefficient on K[s,n]
  __shared__ float qs[64];
  qs[t] = qg2;
  __syncthreads();
  float wacc = 0.f;                          // w[c], c = t
  for (int s2 = 0; s2 < 64; s2++)
    wacc += qs[s2] * Wk[(size_t)(g * 64 + s2) * 64 + t];
  w_all[bg * 64 + t] = wacc;
}

// ---- Kernel M: per g: M = Wk^T Wk, permuted to Mp[g][r][t] (float4);
// ----           cw = colsum_s(Wk) -------------------------------------------
__global__ __launch_bounds__(256) void kM(const float* __restrict__ Wk,
                                          float4* __restrict__ Mp,
                                          float* __restrict__ cw) {
  int g = blockIdx.x; int t = threadIdx.x;
  __shared__ float wk[4096];                 // Wk[g] : [s=64][c=64]
  __shared__ float Ml[64 * 65];              // M padded
  const float* wg = Wk + (size_t)g * 4096;
  #pragma unroll
  for (int i = 0; i < 16; i++) wk[t + 256 * i] = wg[t + 256 * i];
  __syncthreads();
  int c = t & 63, q = t >> 6;                // q wave-uniform -> broadcast reads
  float acc[16];
  #pragma unroll
  for (int i = 0; i < 16; i++) acc[i] = 0.f;
  for (int s = 0; s < 64; s++) {
    float a = wk[s * 64 + c];
    const float* r = &wk[s * 64 + q * 16];
    #pragma unroll
    for (int i = 0; i < 16; i++) acc[i] += a * r[i];
  }
  #pragma unroll
  for (int i = 0; i < 16; i++) Ml[(q * 16 + i) * 65 + c] = acc[i];
  float s2 = 0.f;
  if (t < 64) {
    for (int s = 0; s < 64; s++) s2 += wk[s * 64 + t];
  }
  __syncthreads();
  if (t < 64) cw[g * 64 + t] = s2;
  // Permute: thread t (as a kB thread) needs M[row+i][r*16+col], i=0..3
  int lane = t & 63, wv = t >> 6;
  int row = wv * 16 + ((lane >> 4) << 2);
  int col = lane & 15;
  #pragma unroll
  for (int r = 0; r < 4; r++) {
    float4 mv;
    mv.x = Ml[(row + 0) * 65 + r * 16 + col];
    mv.y = Ml[(row + 1) * 65 + r * 16 + col];
    mv.z = Ml[(row + 2) * 65 + r * 16 + col];
    mv.w = Ml[(row + 3) * 65 + r * 16 + col];
    Mp[(size_t)(g * 4 + r) * 256 + t] = mv;
  }
}

// ---- Kernel B: block = (bg, half): stream 8 chunks of 256 cols.
// ----  per chunk: y[n] = w.x (fp32), SumK partial, bf16 tile -> Gram MFMA ---
__global__ __launch_bounds__(256, 2) void kB(const float* __restrict__ x,
                                             const float* __restrict__ w_all,
                                             const float* __restrict__ cw,
                                             const float4* __restrict__ Mp,
                                             float* __restrict__ y_all,
                                             float* __restrict__ sums_part) {
  int bid = blockIdx.x;
  int bg = bid >> 1, half = bid & 1;
  int b = bg >> 5, g = bg & 31;
  int t = threadIdx.x, lane = t & 63, wv = t >> 6;

  __shared__ unsigned short xt[64 * NSTR];   // bf16 tile [c][n], 33792 B
  __shared__ float ypart[4 * 256];
  __shared__ float red[8];

  const float* wp = w_all + bg * 64 + wv * 16;   // wave-uniform -> s_loads
  const float* cwp = cw + g * 64 + wv * 16;
  const float* xb = x + ((size_t)(b * 2048 + g * 64 + wv * 16)) * NN +
                    half * 2048 + lane * 4;
  unsigned short* xrow = &xt[(wv * 16) * NSTR + lane * 4];

  int rbase = (lane & 15) * NSTR;
  int koff = (lane >> 4) * 8;
  int abase = (wv * 16 + (lane & 15)) * NSTR + koff;

  float zt = 0.f;
  f32x4 acc[4];
  #pragma unroll
  for (int r = 0; r < 4; r++) acc[r] = (f32x4){0.f, 0.f, 0.f, 0.f};

  float4 v0[16], v1[16];
  #pragma unroll
  for (int k = 0; k < 16; k++) v0[k] = *(const float4*)(xb + (size_t)k * NN);

  auto stepB = [&](int i, float4 (&cur)[16], float4 (&nxt)[16]) {
    if (i < 7) {                             // prefetch chunk i+1 (registers)
      const float* xn = xb + (size_t)(i + 1) * 256;
      #pragma unroll
      for (int k = 0; k < 16; k++) nxt[k] = *(const float4*)(xn + (size_t)k * NN);
    }
    float y0 = 0, y1 = 0, y2 = 0, y3 = 0;
    uint2 pk[16];
    #pragma unroll
    for (int k = 0; k < 16; k++) {
      float wc = wp[k], cc = cwp[k];
      float4 vx = cur[k];
      y0 += wc * vx.x; y1 += wc * vx.y; y2 += wc * vx.z; y3 += wc * vx.w;
      zt += cc * (vx.x + vx.y + vx.z + vx.w);
      // bf16 pack: +0x8000 round-half, truncate (0.5 ulp, fine for variance)
      unsigned a0 = __builtin_bit_cast(unsigned, vx.x) + 0x8000u;
      unsigned a1 = __builtin_bit_cast(unsigned, vx.y) + 0x8000u;
      unsigned a2 = __builtin_bit_cast(unsigned, vx.z) + 0x8000u;
      unsigned a3 = __builtin_bit_cast(unsigned, vx.w) + 0x8000u;
      pk[k].x = (a0 >> 16) | (a1 & 0xffff0000u);
      pk[k].y = (a2 >> 16) | (a3 & 0xffff0000u);
    }
    __syncthreads();                         // prev chunk's MFMA done with xt
    #pragma unroll
    for (int k = 0; k < 16; k++) *(uint2*)(xrow + k * NSTR) = pk[k];
    {
      float4 yp; yp.x = y0; yp.y = y1; yp.z = y2; yp.w = y3;
      *(float4*)&ypart[wv * 256 + lane * 4] = yp;
    }
    __syncthreads();                         // xt + ypart ready
    y_all[(size_t)bg * NN + half * 2048 + i * 256 + t] =
        ypart[t] + ypart[256 + t] + ypart[512 + t] + ypart[768 + t];
    #pragma unroll
    for (int kk = 0; kk < 8; kk++) {
      uint4 au = *(const uint4*)&xt[abase + kk * 32];
      bf16x8 af = __builtin_bit_cast(bf16x8, au);
      #pragma unroll
      for (int r = 0; r < 4; r++) {
        uint4 bu = *(const uint4*)&xt[r * 16 * NSTR + rbase + kk * 32 + koff];
        bf16x8 bf = __builtin_bit_cast(bf16x8, bu);
        acc[r] = __builtin_amdgcn_mfma_f32_16x16x32_bf16(af, bf, acc[r], 0, 0, 0);
      }
    }
  };
  #pragma unroll
  for (int ii = 0; ii < 8; ii += 2) {
    stepB(ii, v0, v1);
    stepB(ii + 1, v1, v0);
  }

  // <M, Gram> once per block via pre-permuted Mp: 4 coalesced float4 loads.
  float s2acc = 0.f;
  {
    const float4* mp = Mp + (size_t)g * 1024 + t;
    #pragma unroll
    for (int r = 0; r < 4; r++) {
      float4 mv = mp[r * 256];
      s2acc += acc[r][0] * mv.x + acc[r][1] * mv.y +
               acc[r][2] * mv.z + acc[r][3] * mv.w;
    }
  }
  for (int off = 32; off; off >>= 1) {
    zt += __shfl_xor(zt, off);
    s2acc += __shfl_xor(s2acc, off);
  }
  if (lane == 0) { red[wv] = zt; red[4 + wv] = s2acc; }
  __syncthreads();
  if (t == 0) {
    float* sp = sums_part + (size_t)(half * 256 + bg) * 2;
    sp[0] = red[0] + red[1] + red[2] + red[3];
    sp[1] = red[4] + red[5] + red[6] + red[7];
  }
}

// ---- Kernel C: per bg: rs from summed partials, softmax over 4096 logits ---
__global__ __launch_bounds__(256) void kC(const float* __restrict__ y_all,
                                          const float* __restrict__ sums_part,
                                          float* __restrict__ attn) {
  int bg = blockIdx.x; int t = threadIdx.x;
  float s1 = 0.f, s2 = 0.f;
  for (int i = 0; i < 2; i++) {
    const float* sp = sums_part + (size_t)(i * 256 + bg) * 2;
    s1 += sp[0]; s2 += sp[1];
  }
  float mu = s1 * (1.f / 262144.f);
  float var = s2 * (1.f / 262144.f) - mu * mu;
  float rs = rsqrtf(var + EPS);
  const float* y = y_all + (size_t)bg * NN;
  float l[16];
  float m = -1e30f;
  #pragma unroll
  for (int i = 0; i < 16; i++) {
    l[i] = rs * y[t + 256 * i];
    m = fmaxf(m, l[i]);
  }
  __shared__ float red[8];
  for (int off = 32; off; off >>= 1) m = fmaxf(m, __shfl_xor(m, off));
  int wv = t >> 6, lane = t & 63;
  if (lane == 0) red[wv] = m;
  __syncthreads();
  m = fmaxf(fmaxf(red[0], red[1]), fmaxf(red[2], red[3]));
  float sum = 0.f;
  #pragma unroll
  for (int i = 0; i < 16; i++) { l[i] = __expf(l[i] - m); sum += l[i]; }
  for (int off = 32; off; off >>= 1) sum += __shfl_xor(sum, off);
  if (lane == 0) red[4 + wv] = sum;
  __syncthreads();
  float inv = 1.f / (red[4] + red[5] + red[6] + red[7]);
  float* ao = attn + (size_t)bg * NN;
  #pragma unroll
  for (int i = 0; i < 16; i++) ao[t + 256 * i] = l[i] * inv;
}

// ---- Kernel D: block = (bg, half): outp[half][bg][c] = sum_n attn[n]x[c,n] -
__global__ __launch_bounds__(256, 2) void kD(const float* __restrict__ x,
                                             const float* __restrict__ attn,
                                             float* __restrict__ outp) {
  int bid = blockIdx.x;
  int bg = bid >> 1, half = bid & 1;
  int b = bg >> 5, g = bg & 31;
  int t = threadIdx.x, lane = t & 63, wv = t >> 6;
  const float* xb = x + ((size_t)(b * 2048 + g * 64 + wv * 16)) * NN +
                    half * 2048 + lane * 4;
  const float* ab = attn + (size_t)bg * NN + half * 2048 + lane * 4;

  float p[16];
  #pragma unroll
  for (int k = 0; k < 16; k++) p[k] = 0.f;

  float4 v0[16], v1[16], a0, a1;
  {                                          // chunk 7 first (reverse for L3)
    const float* xn = xb + (size_t)7 * 256;
    a0 = *(const float4*)(ab + 7 * 256);
    #pragma unroll
    for (int k = 0; k < 16; k++) v0[k] = *(const float4*)(xn + (size_t)k * NN);
  }
  auto stepD = [&](int i, float4 (&cur)[16], float4& ac,
                   float4 (&nxt)[16], float4& an) {
    if (i > 0) {                             // prefetch chunk i-1
      const float* xn = xb + (size_t)(i - 1) * 256;
      an = *(const float4*)(ab + (i - 1) * 256);
      #pragma unroll
      for (int k = 0; k < 16; k++) nxt[k] = *(const float4*)(xn + (size_t)k * NN);
    }
    #pragma unroll
    for (int k = 0; k < 16; k++)
      p[k] += ac.x * cur[k].x + ac.y * cur[k].y +
              ac.z * cur[k].z + ac.w * cur[k].w;
  };
  #pragma unroll
  for (int ii = 0; ii < 8; ii += 2) {
    stepD(7 - ii, v0, a0, v1, a1);
    stepD(6 - ii, v1, a1, v0, a0);
  }
  #pragma unroll
  for (int k = 0; k < 16; k++) {
    float r = p[k];
    for (int off = 32; off; off >>= 1) r += __shfl_xor(r, off);
    if (lane == 0) outp[(size_t)half * 16384 + bg * 64 + wv * 16 + k] = r;
  }
}

// ---- Kernel E: out[bg][s] = sum_c (sum_h outp[h][bg][c]) * Wv[g][s][c] -----
__global__ __launch_bounds__(64) void kE(const float* __restrict__ outp,
                                         const float* __restrict__ Wv,
                                         float* __restrict__ out) {
  int bg = blockIdx.x; int g = bg & 31;
  int t = threadIdx.x;
  __shared__ float oc[64];
  __shared__ float wvs[64 * 65];
  oc[t] = outp[bg * 64 + t] + outp[16384 + bg * 64 + t];
  const float* wg = Wv + (size_t)g * 4096;
  for (int i = 0; i < 64; i++) wvs[i * 65 + t] = wg[i * 64 + t];
  __syncthreads();
  float acc = 0.f;
  for (int c = 0; c < 64; c++) acc += wvs[t * 65 + c] * oc[c];
  out[bg * 64 + t] = acc;
}

extern "C" void kernel_launch(void* const* d_in, const int* in_sizes, int n_in,
                              void* d_out, int out_size, void* d_ws, size_t ws_size,
                              hipStream_t stream) {
  const float* x    = (const float*)d_in[0];
  const float* sent = (const float*)d_in[1];
  const float* Wq   = (const float*)d_in[2];
  const float* Wk   = (const float*)d_in[3];
  const float* Wv   = (const float*)d_in[4];
  const float* g1   = (const float*)d_in[5];
  const float* b1   = (const float*)d_in[6];
  const float* g2   = (const float*)d_in[7];
  // d_in[8] = beta2: drops out of softmax (shift-invariance) — unused.
  float* out = (float*)d_out;

  char* ws = (char*)d_ws;
  float*  w_all = (float*)(ws);                 // 256*64*4        = 64 KB
  float*  cw    = (float*)(ws + 65536);         // 32*64*4         = 8 KB
  float4* Mp    = (float4*)(ws + 73728);        // 32*4*256*16     = 512 KB
  float*  sumsp = (float*)(ws + 598016);        // 2*256*2*4       = 4 KB
  float*  outp  = (float*)(ws + 602112);        // 2*256*64*4      = 128 KB
  float*  y_all = (float*)(ws + 733184);        // 256*4096*4      = 4 MB
  float*  attn  = (float*)(ws + 4927488);       // 4 MB

  kA<<<256, 64, 0, stream>>>(sent, Wq, Wk, g1, b1, g2, w_all);
  kM<<<32, 256, 0, stream>>>(Wk, Mp, cw);
  kB<<<512, 256, 0, stream>>>(x, w_all, cw, Mp, y_all, sumsp);
  kC<<<256, 256, 0, stream>>>(y_all, sumsp, attn);
  kD<<<512, 256, 0, stream>>>(x, attn, outp);
  kE<<<256, 64, 0, stream>>>(outp, Wv, out);
}

// Round 5
// 422.167 us; speedup vs baseline: 1.2599x; 1.2599x over previous
//
#include <hip/hip_runtime.h>
#include <stdint.h>

// CondConceptSampler: single-query attention per (b,g) with GroupNorm'd q,k.
// Algebra: GN(k) affine per (b,g) -> softmax(sim) depends only on
// rs * (w . x[:,n]) with w[c] = sum_s qhat[s]*g2[s]*Wk[s,c]; mean/beta drop out.
// rs needs Var(K) over (s,n):  SumK  = <colsum(Wk), rowsum(X)>   (exact, fp32)
//                              SumK2 = <M, X X^T>, M = Wk^T Wk   (bf16 MFMA Gram)
// R5: x-passes use global_load_lds width=16 DMA staging (deep MLP without
// VGPR pressure — registers batches were being serialized by the allocator).
// fp32 tile 64x268 (68.6 KB, 2 blocks/CU), single barrier per block.
//
// B=8 G=32 BW=64 S=64 CD=256 N=4096.  x: [8,2048,4096] fp32 (268 MB).

#define EPS 1e-5f
#define NN 4096
#define XSTR 268   // fp32 tile row stride (1072 B, 16B-aligned)

typedef __bf16 bf16x8 __attribute__((ext_vector_type(8)));
typedef float f32x4 __attribute__((ext_vector_type(4)));

__device__ __forceinline__ void gload16(const float* g, float* l) {
  __builtin_amdgcn_global_load_lds(
      (const __attribute__((address_space(1))) unsigned int*)g,
      (__attribute__((address_space(3))) unsigned int*)l, 16, 0, 0);
}

__device__ __forceinline__ bf16x8 cvt8(float4 a, float4 b) {
  unsigned u0 = __builtin_bit_cast(unsigned, a.x) + 0x8000u;
  unsigned u1 = __builtin_bit_cast(unsigned, a.y) + 0x8000u;
  unsigned u2 = __builtin_bit_cast(unsigned, a.z) + 0x8000u;
  unsigned u3 = __builtin_bit_cast(unsigned, a.w) + 0x8000u;
  unsigned u4 = __builtin_bit_cast(unsigned, b.x) + 0x8000u;
  unsigned u5 = __builtin_bit_cast(unsigned, b.y) + 0x8000u;
  unsigned u6 = __builtin_bit_cast(unsigned, b.z) + 0x8000u;
  unsigned u7 = __builtin_bit_cast(unsigned, b.w) + 0x8000u;
  uint4 r;
  r.x = (u0 >> 16) | (u1 & 0xffff0000u);
  r.y = (u2 >> 16) | (u3 & 0xffff0000u);
  r.z = (u4 >> 16) | (u5 & 0xffff0000u);
  r.w = (u6 >> 16) | (u7 & 0xffff0000u);
  return __builtin_bit_cast(bf16x8, r);
}

// ---- Kernel A: q-path -> w_all[bg][c], 4 waves ----------------------------
__global__ __launch_bounds__(256) void kA(const float* __restrict__ sent,
                                          const float* __restrict__ Wq,
                                          const float* __restrict__ Wk,
                                          const float* __restrict__ g1,
                                          const float* __restrict__ b1,
                                          const float* __restrict__ g2,
                                          float* __restrict__ w_all) {
  int bg = blockIdx.x; int b = bg >> 5; int g = bg & 31;
  int t = threadIdx.x, lane = t & 63, wv = t >> 6;
  __shared__ float qp[256], qs[64], wpp[256];
  // phase 1: q[s=lane] partial over c-quarter wv
  const float* se = sent + b * 256 + wv * 64;        // wave-uniform
  const float* wqrow = Wq + (size_t)(g * 64 + lane) * 256 + wv * 64;
  float acc = 0.f;
  #pragma unroll
  for (int c = 0; c < 64; c += 4) {
    float4 w4 = *(const float4*)(wqrow + c);
    acc += se[c] * w4.x + se[c + 1] * w4.y + se[c + 2] * w4.z + se[c + 3] * w4.w;
  }
  qp[wv * 64 + lane] = acc;
  __syncthreads();
  if (wv == 0) {
    float q = qp[lane] + qp[64 + lane] + qp[128 + lane] + qp[192 + lane];
    float s = q;
    for (int off = 32; off; off >>= 1) s += __shfl_xor(s, off);
    float mu = s * (1.f / 64.f);
    float d = q - mu;
    float v = d * d;
    for (int off = 32; off; off >>= 1) v += __shfl_xor(v, off);
    float rsq = rsqrtf(v * (1.f / 64.f) + EPS);
    int gs = g * 64 + lane;
    qs[lane] = (d * rsq * g1[gs] + b1[gs]) * g2[gs];
  }
  __syncthreads();
  // phase 2: w[c=lane] = sum_s qs[s]*Wk[g][s][c], s split by wave
  const float* wkb = Wk + (size_t)(g * 64 + wv * 16) * 64 + lane;
  float wa = 0.f;
  #pragma unroll
  for (int s2 = 0; s2 < 16; s2++) wa += qs[wv * 16 + s2] * wkb[s2 * 64];
  wpp[wv * 64 + lane] = wa;
  __syncthreads();
  if (wv == 0)
    w_all[bg * 64 + lane] = wpp[lane] + wpp[64 + lane] + wpp[128 + lane] + wpp[192 + lane];
}

// ---- Kernel M: per g: M = Wk^T Wk, permuted to Mp[g][r][t] (float4);
// ----           cw = colsum_s(Wk) ------------------------------------------
__global__ __launch_bounds__(256) void kM(const float* __restrict__ Wk,
                                          float4* __restrict__ Mp,
                                          float* __restrict__ cw) {
  int g = blockIdx.x; int t = threadIdx.x;
  __shared__ float wk[4096];                 // Wk[g] : [s=64][c=64]
  __shared__ float Ml[64 * 65];              // M padded
  const float* wg = Wk + (size_t)g * 4096;
  #pragma unroll
  for (int i = 0; i < 16; i++) wk[t + 256 * i] = wg[t + 256 * i];
  __syncthreads();
  int c = t & 63, q = t >> 6;                // q wave-uniform -> broadcast reads
  float acc[16];
  #pragma unroll
  for (int i = 0; i < 16; i++) acc[i] = 0.f;
  for (int s = 0; s < 64; s++) {
    float a = wk[s * 64 + c];
    const float* r = &wk[s * 64 + q * 16];
    #pragma unroll
    for (int i = 0; i < 16; i++) acc[i] += a * r[i];
  }
  #pragma unroll
  for (int i = 0; i < 16; i++) Ml[(q * 16 + i) * 65 + c] = acc[i];
  float s2 = 0.f;
  if (t < 64) {
    for (int s = 0; s < 64; s++) s2 += wk[s * 64 + t];
  }
  __syncthreads();
  if (t < 64) cw[g * 64 + t] = s2;
  // Permute for kB: thread t needs M[row+i][r*16+col]
  int lane = t & 63, wv = t >> 6;
  int row = wv * 16 + ((lane >> 4) << 2);
  int col = lane & 15;
  #pragma unroll
  for (int r = 0; r < 4; r++) {
    float4 mv;
    mv.x = Ml[(row + 0) * 65 + r * 16 + col];
    mv.y = Ml[(row + 1) * 65 + r * 16 + col];
    mv.z = Ml[(row + 2) * 65 + r * 16 + col];
    mv.w = Ml[(row + 3) * 65 + r * 16 + col];
    Mp[(size_t)(g * 4 + r) * 256 + t] = mv;
  }
}

// ---- Kernel B: block = (bg, chunk 256): DMA-stage fp32 tile; y = w.x,
// ----  z = cw.x (column walk), SumK2 partial via bf16 Gram MFMA ------------
__global__ __launch_bounds__(256, 2) void kB(const float* __restrict__ x,
                                             const float* __restrict__ w_all,
                                             const float* __restrict__ cw,
                                             const float4* __restrict__ Mp,
                                             float* __restrict__ y_all,
                                             float* __restrict__ sums_part) {
  int bid = blockIdx.x;
  int bg = bid >> 4, ch = bid & 15;
  int b = bg >> 5, g = bg & 31;
  int t = threadIdx.x, lane = t & 63, wv = t >> 6;
  int n0 = ch * 256;

  __shared__ float xt[64 * XSTR];            // 68608 B fp32 tile [c][n]
  __shared__ float wl[64], cwl[64];
  __shared__ float red[8];

  if (t < 64) { wl[t] = w_all[bg * 64 + t]; cwl[t] = cw[g * 64 + t]; }

  // DMA staging: wave wv stages rows wv*16..wv*16+15 (1 KB each, lane x 16B).
  const float* xrow = x + ((size_t)(b * 2048 + g * 64 + wv * 16)) * NN + n0 + lane * 4;
  #pragma unroll
  for (int k = 0; k < 16; k++)
    gload16(xrow + (size_t)k * NN, &xt[(wv * 16 + k) * XSTR]);
  __syncthreads();                           // drains DMA (vmcnt) + wl/cwl

  // y & z for column t (contiguous lanes -> conflict-free LDS reads)
  float y = 0.f, z = 0.f;
  #pragma unroll 8
  for (int c = 0; c < 64; c++) {
    float v = xt[c * XSTR + t];
    y += wl[c] * v;
    z += cwl[c] * v;
  }
  y_all[(size_t)bg * NN + n0 + t] = y;

  // Gram MFMA: wave wv computes tile-row wv of C = X X^T (4 16x16 tiles).
  int rbase = (lane & 15) * XSTR + (lane >> 4) * 8;
  int abase = (wv * 16 + (lane & 15)) * XSTR + (lane >> 4) * 8;
  f32x4 acc[4];
  #pragma unroll
  for (int r = 0; r < 4; r++) acc[r] = (f32x4){0.f, 0.f, 0.f, 0.f};
  #pragma unroll
  for (int kk = 0; kk < 8; kk++) {
    float4 a0 = *(const float4*)&xt[abase + kk * 32];
    float4 a1 = *(const float4*)&xt[abase + kk * 32 + 4];
    bf16x8 af = cvt8(a0, a1);
    #pragma unroll
    for (int r = 0; r < 4; r++) {
      float4 b0 = *(const float4*)&xt[r * 16 * XSTR + rbase + kk * 32];
      float4 b1 = *(const float4*)&xt[r * 16 * XSTR + rbase + kk * 32 + 4];
      acc[r] = __builtin_amdgcn_mfma_f32_16x16x32_bf16(af, cvt8(b0, b1), acc[r], 0, 0, 0);
    }
  }
  // <M, Gram> via pre-permuted Mp: 4 coalesced float4 loads.
  float s2acc = 0.f;
  {
    const float4* mp = Mp + (size_t)g * 1024 + t;
    #pragma unroll
    for (int r = 0; r < 4; r++) {
      float4 mv = mp[r * 256];
      s2acc += acc[r][0] * mv.x + acc[r][1] * mv.y +
               acc[r][2] * mv.z + acc[r][3] * mv.w;
    }
  }
  for (int off = 32; off; off >>= 1) {
    z += __shfl_xor(z, off);
    s2acc += __shfl_xor(s2acc, off);
  }
  if (lane == 0) { red[wv] = z; red[4 + wv] = s2acc; }
  __syncthreads();
  if (t == 0) {
    float* sp = sums_part + (size_t)(ch * 256 + bg) * 2;
    sp[0] = red[0] + red[1] + red[2] + red[3];
    sp[1] = red[4] + red[5] + red[6] + red[7];
  }
}

// ---- Kernel C: per bg: rs from summed partials, softmax over 4096 logits ---
__global__ __launch_bounds__(256) void kC(const float* __restrict__ y_all,
                                          const float* __restrict__ sums_part,
                                          float* __restrict__ attn) {
  int bg = blockIdx.x; int t = threadIdx.x;
  float s1 = 0.f, s2 = 0.f;
  for (int i = 0; i < 16; i++) {
    const float* sp = sums_part + (size_t)(i * 256 + bg) * 2;
    s1 += sp[0]; s2 += sp[1];
  }
  float mu = s1 * (1.f / 262144.f);
  float var = s2 * (1.f / 262144.f) - mu * mu;
  float rs = rsqrtf(var + EPS);
  const float* y = y_all + (size_t)bg * NN;
  float l[16];
  float m = -1e30f;
  #pragma unroll
  for (int i = 0; i < 16; i++) {
    l[i] = rs * y[t + 256 * i];
    m = fmaxf(m, l[i]);
  }
  __shared__ float red[8];
  for (int off = 32; off; off >>= 1) m = fmaxf(m, __shfl_xor(m, off));
  int wv = t >> 6, lane = t & 63;
  if (lane == 0) red[wv] = m;
  __syncthreads();
  m = fmaxf(fmaxf(red[0], red[1]), fmaxf(red[2], red[3]));
  float sum = 0.f;
  #pragma unroll
  for (int i = 0; i < 16; i++) { l[i] = __expf(l[i] - m); sum += l[i]; }
  for (int off = 32; off; off >>= 1) sum += __shfl_xor(sum, off);
  if (lane == 0) red[4 + wv] = sum;
  __syncthreads();
  float inv = 1.f / (red[4] + red[5] + red[6] + red[7]);
  float* ao = attn + (size_t)bg * NN;
  #pragma unroll
  for (int i = 0; i < 16; i++) ao[t + 256 * i] = l[i] * inv;
}

// ---- Kernel D: block = (bg, chunk): DMA-stage tile + attn chunk; weighted
// ----  column sum -> outp[ch][bg][c] ---------------------------------------
__global__ __launch_bounds__(256, 2) void kD(const float* __restrict__ x,
                                             const float* __restrict__ attn,
                                             float* __restrict__ outp) {
  int bid = blockIdx.x;
  int bg = 255 - (bid >> 4), ch = 15 - (bid & 15);  // reverse for L3 reuse
  int b = bg >> 5, g = bg & 31;
  int t = threadIdx.x, lane = t & 63, wv = t >> 6;
  int n0 = ch * 256;

  __shared__ float xt[64 * XSTR];            // 68608 B
  __shared__ float al[256];
  __shared__ float pp[256];

  const float* xrow = x + ((size_t)(b * 2048 + g * 64 + wv * 16)) * NN + n0 + lane * 4;
  if (wv == 0) gload16(attn + (size_t)bg * NN + n0 + lane * 4, al);
  #pragma unroll
  for (int k = 0; k < 16; k++)
    gload16(xrow + (size_t)k * NN, &xt[(wv * 16 + k) * XSTR]);
  __syncthreads();

  // thread: row c = lane, n-quarter = wv (attn reads wave-uniform -> bcast)
  float p = 0.f;
  const float* xr = &xt[lane * XSTR + wv * 64];
  const float* ar = &al[wv * 64];
  #pragma unroll
  for (int j = 0; j < 64; j += 4) {
    float4 xv = *(const float4*)(xr + j);
    p += ar[j] * xv.x + ar[j + 1] * xv.y + ar[j + 2] * xv.z + ar[j + 3] * xv.w;
  }
  pp[wv * 64 + lane] = p;
  __syncthreads();
  if (t < 64)
    outp[(size_t)ch * 16384 + bg * 64 + t] =
        pp[t] + pp[64 + t] + pp[128 + t] + pp[192 + t];
}

// ---- Kernel E: out[bg][s] = sum_c (sum_ch outp[ch][bg][c]) * Wv[g][s][c] --
__global__ __launch_bounds__(256) void kE(const float* __restrict__ outp,
                                          const float* __restrict__ Wv,
                                          float* __restrict__ out) {
  int bg = blockIdx.x; int g = bg & 31;
  int t = threadIdx.x, lane = t & 63, wv = t >> 6;
  __shared__ float oc[64];
  __shared__ float wvs[64 * 65];
  __shared__ float ep[256];
  if (t < 64) {
    float s = 0.f;
    #pragma unroll
    for (int j = 0; j < 16; j++) s += outp[j * 16384 + bg * 64 + t];
    oc[t] = s;
  }
  const float* wg = Wv + (size_t)g * 4096;
  #pragma unroll
  for (int i = 0; i < 16; i++) {
    int idx = i * 256 + t;
    wvs[(idx >> 6) * 65 + (idx & 63)] = wg[idx];
  }
  __syncthreads();
  float acc = 0.f;
  #pragma unroll
  for (int j = 0; j < 16; j++)
    acc += wvs[lane * 65 + wv * 16 + j] * oc[wv * 16 + j];
  ep[wv * 64 + lane] = acc;
  __syncthreads();
  if (wv == 0)
    out[bg * 64 + lane] = ep[lane] + ep[64 + lane] + ep[128 + lane] + ep[192 + lane];
}

extern "C" void kernel_launch(void* const* d_in, const int* in_sizes, int n_in,
                              void* d_out, int out_size, void* d_ws, size_t ws_size,
                              hipStream_t stream) {
  const float* x    = (const float*)d_in[0];
  const float* sent = (const float*)d_in[1];
  const float* Wq   = (const float*)d_in[2];
  const float* Wk   = (const float*)d_in[3];
  const float* Wv   = (const float*)d_in[4];
  const float* g1   = (const float*)d_in[5];
  const float* b1   = (const float*)d_in[6];
  const float* g2   = (const float*)d_in[7];
  // d_in[8] = beta2: drops out of softmax (shift-invariance) — unused.
  float* out = (float*)d_out;

  char* ws = (char*)d_ws;
  float*  w_all = (float*)(ws);                 // 64 KB
  float*  cw    = (float*)(ws + 65536);         // 8 KB
  float4* Mp    = (float4*)(ws + 73728);        // 512 KB
  float*  sumsp = (float*)(ws + 598016);        // 32 KB
  float*  outp  = (float*)(ws + 630784);        // 1 MB
  float*  y_all = (float*)(ws + 1679360);       // 4 MB
  float*  attn  = (float*)(ws + 5873664);       // 4 MB

  kA<<<256, 256, 0, stream>>>(sent, Wq, Wk, g1, b1, g2, w_all);
  kM<<<32, 256, 0, stream>>>(Wk, Mp, cw);
  kB<<<4096, 256, 0, stream>>>(x, w_all, cw, Mp, y_all, sumsp);
  kC<<<256, 256, 0, stream>>>(y_all, sumsp, attn);
  kD<<<4096, 256, 0, stream>>>(x, attn, outp);
  kE<<<256, 256, 0, stream>>>(outp, Wv, out);
}